// Round 10
// baseline (329.605 us; speedup 1.0000x reference)
//
#include <hip/hip_runtime.h>
#include <hip/hip_bf16.h>
#include <cstddef>

// Fused 3-layer LSTM, wavefront-pipelined, swapped-operand MFMA, 12 waves.
// R10: TWO-PHASE iteration with register prefetch across the barrier:
//   [compute t from PREFETCHED frags -> write h(t)]  BAR1
//   [prefetch A-frags for t+1]                        BAR2
// Single-buffered act tiles (BAR1 = h(t) complete; BAR2 = readers done before
// next iter's writers). Compute phase has ZERO LDS-read dependency.
// Roles: w0-2 L0 4 tiles each (w2 stages x, 2-iter pipeline); w3-6 L1 NT=3;
// w7-10 L2 NT=3; w11 orphan = tile 12 of L0+L1+L2.
// Skew: iter it -> L0@t=it, L1@t=it-1, L2@t=it-2.
// 2-term split: weights (hi,lo) bf16, activations RNE bf16.
// Act layout fragment-major: addr(k,b) = (k>>3)*128 + b*8 + (k&7) shorts.
// Bias rides act==1.0 column: L0 k=58, L1/L2 k=100.

#define T_STEPS 256
#define BTOT    4096
#define NTHR    768

typedef __attribute__((ext_vector_type(8))) short short8;
typedef __attribute__((ext_vector_type(4))) float f32x4;

#define BAR() do { \
    asm volatile("s_waitcnt lgkmcnt(0)" ::: "memory"); \
    __builtin_amdgcn_sched_barrier(0); \
    __builtin_amdgcn_s_barrier(); \
    __builtin_amdgcn_sched_barrier(0); \
} while (0)

__device__ __forceinline__ float fast_sigmoid(float x) {
    float e = __builtin_amdgcn_exp2f(-1.4426950408889634f * x);
    return __builtin_amdgcn_rcpf(1.0f + e);
}
__device__ __forceinline__ float fast_tanh(float x) {
    float e = __builtin_amdgcn_exp2f(2.8853900817779268f * x);
    return 1.0f - 2.0f * __builtin_amdgcn_rcpf(1.0f + e);
}
__device__ __forceinline__ unsigned short f2bf(float x) {     // RNE
    union { __hip_bfloat16 b; unsigned short s; } u;
    u.b = __float2bfloat16(x);
    return u.s;
}
__device__ __forceinline__ float bf2f(unsigned short s) {
    union { unsigned u; float f; } v; v.u = (unsigned)s << 16; return v.f;
}
__device__ __forceinline__ float cell_upd(f32x4 g, float& cst) {
    float ig = fast_sigmoid(g[0]);
    float fg = fast_sigmoid(g[1]);
    float gg = fast_tanh(g[2]);
    float og = fast_sigmoid(g[3]);
    float c  = fmaf(fg, cst, ig * gg);
    cst = c;
    return og * fast_tanh(c);
}

// Weights -> (hi,lo) frags. K-packed [w_ih(XK) | w_hh(50) | bias@BIASK].
// Row N' = (T0+q)*16 + (lane&15), k = ks*32 + (lane>>4)*8 + e.
template<int NT, int KS, int XK, int BIASK>
__device__ __forceinline__ void load_wb(int T0, int lane,
    const float* __restrict__ w_ih, const float* __restrict__ w_hh,
    const float* __restrict__ b_ih, const float* __restrict__ b_hh,
    short8 (&Wh)[NT][KS], short8 (&Wl)[NT][KS])
{
    const int m = lane & 15, kg = lane >> 4;
    #pragma unroll
    for (int q = 0; q < NT; ++q) {
        int gp = (T0 + q) * 16 + m;
        int gr = (gp < 200) ? ((gp & 3) * 50 + (gp >> 2)) : -1;
        #pragma unroll
        for (int ks = 0; ks < KS; ++ks)
            #pragma unroll
            for (int e = 0; e < 8; ++e) {
                int k = ks * 32 + kg * 8 + e;
                float v = 0.0f;
                if (gr >= 0) {
                    if (k < XK) v = w_ih[gr * XK + k];
                    else if (k < XK + 50) v = w_hh[gr * 50 + (k - XK)];
                    else if (k == BIASK) v = b_ih[gr] + b_hh[gr];
                }
                unsigned short hb = f2bf(v);
                Wh[q][ks][e] = (short)hb;
                Wl[q][ks][e] = (short)f2bf(v - bf2f(hb));
            }
    }
}

template<int KS>
__device__ __forceinline__ void prefetch(const short* Ar, int lane, short8 (&Ap)[KS]) {
    const int b = lane & 15, kg = lane >> 4;
    #pragma unroll
    for (int ks = 0; ks < KS; ++ks)
        Ap[ks] = *(const short8*)&Ar[(ks * 4 + kg) * 128 + b * 8];
}

// Compute phase: MFMA entirely from prefetched frags, in-register cell update,
// bf16 h writes (own buffer at HK+n; boundary x-part at k=n if WRB).
template<int T0, int NT, int KS, int HK, bool WRB, bool LASTL>
__device__ __forceinline__ void compute_step(
    int t, int lane,
    short* Aw, short* Ax, float* hfp,
    const short8 (&Ap)[KS],
    const short8 (&Wh)[NT][KS], const short8 (&Wl)[NT][KS],
    float (&cst)[NT])
{
    const int b = lane & 15, kg = lane >> 4;

    f32x4 acc[NT];
    #pragma unroll
    for (int q = 0; q < NT; ++q) acc[q] = (f32x4){0.0f, 0.0f, 0.0f, 0.0f};

    #pragma unroll
    for (int ks = 0; ks < KS; ++ks)
        #pragma unroll
        for (int q = 0; q < NT; ++q)
            acc[q] = __builtin_amdgcn_mfma_f32_16x16x32_bf16(Wh[q][ks], Ap[ks], acc[q], 0, 0, 0);
    #pragma unroll
    for (int ks = 0; ks < KS; ++ks)
        #pragma unroll
        for (int q = 0; q < NT; ++q)
            acc[q] = __builtin_amdgcn_mfma_f32_16x16x32_bf16(Wl[q][ks], Ap[ks], acc[q], 0, 0, 0);

    #pragma unroll
    for (int q = 0; q < NT; ++q) {
        int n = (T0 + q) * 4 + kg;
        if (n < 50) {
            float h = cell_upd(acc[q], cst[q]);
            unsigned short hb = f2bf(h);
            int k = HK + n;
            Aw[(k >> 3) * 128 + b * 8 + (k & 7)] = (short)hb;
            if (WRB)
                Ax[(n >> 3) * 128 + b * 8 + (n & 7)] = (short)hb;
            if (LASTL && t == T_STEPS - 1) hfp[b * 56 + n] = h;
        }
    }
}

// L0 role: 4 tiles, skew 0. XST: x staging with 2-iter register pipeline.
template<int T0, bool XST>
__device__ void role_l0(int lane, int b0, const float* __restrict__ xf,
    const float* w_ih, const float* w_hh, const float* b_ih, const float* b_hh,
    short* A0, short* A1)
{
    short8 Wh[4][2], Wl[4][2];
    load_wb<4, 2, 8, 58>(T0, lane, w_ih, w_hh, b_ih, b_hh, Wh, Wl);
    float cst[4] = {0.0f, 0.0f, 0.0f, 0.0f};
    short8 Ap[2];
    const int bb = lane & 15, kg = lane >> 4;

    float xp[2][8];
    if (XST && kg == 0) {
        #pragma unroll
        for (int s = 0; s < 2; ++s) {
            const float* xr = &xf[((size_t)(b0 + bb) * T_STEPS + (1 + s)) * 8];
            *(float4*)&xp[s][0] = *(const float4*)xr;
            *(float4*)&xp[s][4] = *(const float4*)(xr + 4);
        }
    }

    for (int it = -1; it < T_STEPS + 2; ++it) {
        if (0 <= it && it < T_STEPS)
            compute_step<T0, 4, 2, 8, true, false>(it, lane, A0, A1, nullptr, Ap, Wh, Wl, cst);
        if (XST && kg == 0 && it >= 0) {
            if (it + 1 < T_STEPS) {               // commit x(it+1) (k=0..7, granule 0)
                short8 hi;
                #pragma unroll
                for (int e = 0; e < 8; ++e) hi[e] = (short)f2bf(xp[it & 1][e]);
                *(short8*)&A0[bb * 8] = hi;
            }
            if (it + 3 < T_STEPS) {               // refill -> committed at it+2
                const float* xr = &xf[((size_t)(b0 + bb) * T_STEPS + (it + 3)) * 8];
                *(float4*)&xp[it & 1][0] = *(const float4*)xr;
                *(float4*)&xp[it & 1][4] = *(const float4*)(xr + 4);
            }
        }
        BAR();
        if (0 <= it + 1 && it + 1 < T_STEPS) prefetch<2>(A0, lane, Ap);
        BAR();
    }
}

// Mid-layer role, NT=3. LASTL: L2 (skew 2, hf at t=255); else L1 (-> A2 x-part).
template<int T0, bool LASTL>
__device__ void role_mid(int lane,
    const float* w_ih, const float* w_hh, const float* b_ih, const float* b_hh,
    short* Ar, short* Ax, float* hfp)
{
    constexpr int SKEW = LASTL ? 2 : 1;
    short8 Wh[3][4], Wl[3][4];
    load_wb<3, 4, 50, 100>(T0, lane, w_ih, w_hh, b_ih, b_hh, Wh, Wl);
    float cst[3] = {0.0f, 0.0f, 0.0f};
    short8 Ap[4];

    for (int it = -1; it < T_STEPS + 2; ++it) {
        int t = it - SKEW;
        if (0 <= t && t < T_STEPS)
            compute_step<T0, 3, 4, 50, !LASTL, LASTL>(t, lane, Ar, Ax, hfp, Ap, Wh, Wl, cst);
        BAR();
        if (0 <= t + 1 && t + 1 < T_STEPS) prefetch<4>(Ar, lane, Ap);
        BAR();
    }
}

// Orphan: tile 12 of L0 (skew 0), L1 (skew 1), L2 (skew 2).
__device__ void role_orphan(int lane,
    const float* w_ih0, const float* w_hh0, const float* b_ih0, const float* b_hh0,
    const float* w_ih1, const float* w_hh1, const float* b_ih1, const float* b_hh1,
    const float* w_ih2, const float* w_hh2, const float* b_ih2, const float* b_hh2,
    short* A0, short* A1, short* A2, float* hfp)
{
    short8 W0h[1][2], W0l[1][2], W1h[1][4], W1l[1][4], W2h[1][4], W2l[1][4];
    load_wb<1, 2, 8, 58>(12, lane, w_ih0, w_hh0, b_ih0, b_hh0, W0h, W0l);
    load_wb<1, 4, 50, 100>(12, lane, w_ih1, w_hh1, b_ih1, b_hh1, W1h, W1l);
    load_wb<1, 4, 50, 100>(12, lane, w_ih2, w_hh2, b_ih2, b_hh2, W2h, W2l);
    float c0[1] = {0.0f}, c1[1] = {0.0f}, c2[1] = {0.0f};
    short8 Ap0[2], Ap1[4], Ap2[4];

    for (int it = -1; it < T_STEPS + 2; ++it) {
        int t0 = it, t1 = it - 1, t2 = it - 2;
        if (0 <= t0 && t0 < T_STEPS)
            compute_step<12, 1, 2, 8, true, false>(t0, lane, A0, A1, nullptr, Ap0, W0h, W0l, c0);
        if (0 <= t1 && t1 < T_STEPS)
            compute_step<12, 1, 4, 50, true, false>(t1, lane, A1, A2, nullptr, Ap1, W1h, W1l, c1);
        if (0 <= t2 && t2 < T_STEPS)
            compute_step<12, 1, 4, 50, false, true>(t2, lane, A2, nullptr, hfp, Ap2, W2h, W2l, c2);
        BAR();
        if (t0 + 1 >= 0 && t0 + 1 < T_STEPS) prefetch<2>(A0, lane, Ap0);
        if (t1 + 1 >= 0 && t1 + 1 < T_STEPS) prefetch<4>(A1, lane, Ap1);
        if (t2 + 1 >= 0 && t2 + 1 < T_STEPS) prefetch<4>(A2, lane, Ap2);
        BAR();
    }
}

__global__ __launch_bounds__(NTHR) void lstm_fused(
    const float* __restrict__ xf,
    const float* w_ih0, const float* w_hh0, const float* b_ih0, const float* b_hh0,
    const float* w_ih1, const float* w_hh1, const float* b_ih1, const float* b_hh1,
    const float* w_ih2, const float* w_hh2, const float* b_ih2, const float* b_hh2,
    const float* __restrict__ w_fc, const float* __restrict__ b_fc,
    float* __restrict__ out)
{
    __shared__ __align__(16) short A0[1024];     // L0 act (K=64), single buffer
    __shared__ __align__(16) short A1[2048];     // L1 act (K=128)
    __shared__ __align__(16) short A2[2048];     // L2 act (K=128)
    __shared__ __align__(16) float hf[16 * 56];

    const int tid  = threadIdx.x;
    const int lane = tid & 63;
    const int wid  = tid >> 6;
    const int b0   = blockIdx.x * 16;

    for (int i = tid; i < 1024; i += NTHR) A0[i] = 0;
    for (int i = tid; i < 2048; i += NTHR) { A1[i] = 0; A2[i] = 0; }
    __syncthreads();

    // bias act columns = 1.0; x(0) -> A0 x-part
    if (tid < 16) {
        int b = tid;
        A0[7 * 128 + b * 8 + 2]  = (short)0x3F80;     // k=58
        A1[12 * 128 + b * 8 + 4] = (short)0x3F80;     // k=100
        A2[12 * 128 + b * 8 + 4] = (short)0x3F80;
        #pragma unroll
        for (int j = 0; j < 8; ++j) {
            float v = xf[((size_t)(b0 + b) * T_STEPS + 0) * 8 + j];
            A0[b * 8 + j] = (short)f2bf(v);
        }
    }
    __syncthreads();

    if      (wid == 0)  role_l0<0, false>(lane, b0, xf, w_ih0, w_hh0, b_ih0, b_hh0, A0, A1);
    else if (wid == 1)  role_l0<4, false>(lane, b0, xf, w_ih0, w_hh0, b_ih0, b_hh0, A0, A1);
    else if (wid == 2)  role_l0<8, true >(lane, b0, xf, w_ih0, w_hh0, b_ih0, b_hh0, A0, A1);
    else if (wid == 3)  role_mid<0, false>(lane, w_ih1, w_hh1, b_ih1, b_hh1, A1, A2, nullptr);
    else if (wid == 4)  role_mid<3, false>(lane, w_ih1, w_hh1, b_ih1, b_hh1, A1, A2, nullptr);
    else if (wid == 5)  role_mid<6, false>(lane, w_ih1, w_hh1, b_ih1, b_hh1, A1, A2, nullptr);
    else if (wid == 6)  role_mid<9, false>(lane, w_ih1, w_hh1, b_ih1, b_hh1, A1, A2, nullptr);
    else if (wid == 7)  role_mid<0, true >(lane, w_ih2, w_hh2, b_ih2, b_hh2, A2, nullptr, hf);
    else if (wid == 8)  role_mid<3, true >(lane, w_ih2, w_hh2, b_ih2, b_hh2, A2, nullptr, hf);
    else if (wid == 9)  role_mid<6, true >(lane, w_ih2, w_hh2, b_ih2, b_hh2, A2, nullptr, hf);
    else if (wid == 10) role_mid<9, true >(lane, w_ih2, w_hh2, b_ih2, b_hh2, A2, nullptr, hf);
    else                role_orphan(lane,
                            w_ih0, w_hh0, b_ih0, b_hh0,
                            w_ih1, w_hh1, b_ih1, b_hh1,
                            w_ih2, w_hh2, b_ih2, b_hh2,
                            A0, A1, A2, hf);

    __syncthreads();

    if (tid < 96) {
        int b = tid / 6, o = tid - b * 6;
        float a = b_fc[o];
        #pragma unroll
        for (int n = 0; n < 50; ++n)
            a = fmaf(w_fc[o * 50 + n], hf[b * 56 + n], a);
        out[(size_t)(b0 + b) * 6 + o] = a;
    }
}

extern "C" void kernel_launch(void* const* d_in, const int* in_sizes, int n_in,
                              void* d_out, int out_size, void* d_ws, size_t ws_size,
                              hipStream_t stream) {
    (void)in_sizes; (void)n_in; (void)d_ws; (void)ws_size; (void)out_size;

    const float* x     = (const float*)d_in[0];
    const float* w_ih0 = (const float*)d_in[1];
    const float* w_hh0 = (const float*)d_in[2];
    const float* b_ih0 = (const float*)d_in[3];
    const float* b_hh0 = (const float*)d_in[4];
    const float* w_ih1 = (const float*)d_in[5];
    const float* w_hh1 = (const float*)d_in[6];
    const float* b_ih1 = (const float*)d_in[7];
    const float* b_hh1 = (const float*)d_in[8];
    const float* w_ih2 = (const float*)d_in[9];
    const float* w_hh2 = (const float*)d_in[10];
    const float* b_ih2 = (const float*)d_in[11];
    const float* b_hh2 = (const float*)d_in[12];
    const float* w_fc  = (const float*)d_in[13];
    const float* b_fc  = (const float*)d_in[14];
    float* out = (float*)d_out;

    lstm_fused<<<dim3(BTOT / 16), dim3(NTHR), 0, stream>>>(
        x, w_ih0, w_hh0, b_ih0, b_hh0, w_ih1, w_hh1, b_ih1, b_hh1,
        w_ih2, w_hh2, b_ih2, b_hh2, w_fc, b_fc, out);
}

// Round 11
// 311.821 us; speedup vs baseline: 1.0570x; 1.0570x over previous
//
#include <hip/hip_runtime.h>
#include <hip/hip_bf16.h>
#include <cstddef>

// Fused 3-layer LSTM, wavefront-pipelined, swapped-operand MFMA.
// R11: 16 waves (4/SIMD) on R9's batched-read step structure + shared
// single-write h regions (granule-gather; no boundary double-writes).
//
// Act regions (granule = 8 k x 16 b = 128 shorts, lane-linear reads):
//   H0[2], H1[3], H2[2]; each buf = 9 granules:
//     g0 = x (L0 input) or zero; g1..g7 = h units 0..55 (unit u -> g 1+(u>>3),
//     pos u&7; act==1.0 bias column at g7 pos2 = unit index 50); g8 = zero pad.
//   Layer L reads its own h at slots (granules s), next layer reads the SAME
//   region at granules 1+s (its "x-side"). h written ONCE per step.
// Buffering: h0(t) in H0[(t+1)&1]; h1(t) in H1[t%3] (3 bufs: two readers at
// different skews); h2(t) in H2[t&1]. x(t) in H0[t&1] g0.
// Roles: w0-2 L0 NT=4 (w2 stages x); w4-9 L1 NT=2; w10-15 L2 NT=2;
// w3 orphan = tile 12 of L0+L1+L2. Skew: iter it -> L0@it, L1@it-1, L2@it-2.
// One s_barrier per iter. 2-term weight split (hi,lo), acts RNE bf16.

#define T_STEPS 256
#define BTOT    4096
#define NTHR    1024
#define GS      128          // shorts per granule
#define BUFSZ   (9 * GS)     // shorts per region buffer

typedef __attribute__((ext_vector_type(8))) short short8;
typedef __attribute__((ext_vector_type(4))) float f32x4;

#define BAR() do { \
    asm volatile("s_waitcnt lgkmcnt(0)" ::: "memory"); \
    __builtin_amdgcn_sched_barrier(0); \
    __builtin_amdgcn_s_barrier(); \
    __builtin_amdgcn_sched_barrier(0); \
} while (0)

__device__ __forceinline__ float fast_sigmoid(float x) {
    float e = __builtin_amdgcn_exp2f(-1.4426950408889634f * x);
    return __builtin_amdgcn_rcpf(1.0f + e);
}
__device__ __forceinline__ float fast_tanh(float x) {
    float e = __builtin_amdgcn_exp2f(2.8853900817779268f * x);
    return 1.0f - 2.0f * __builtin_amdgcn_rcpf(1.0f + e);
}
__device__ __forceinline__ unsigned short f2bf(float x) {     // RNE
    union { __hip_bfloat16 b; unsigned short s; } u;
    u.b = __float2bfloat16(x);
    return u.s;
}
__device__ __forceinline__ float bf2f(unsigned short s) {
    union { unsigned u; float f; } v; v.u = (unsigned)s << 16; return v.f;
}
__device__ __forceinline__ float cell_upd(f32x4 g, float& cst) {
    float ig = fast_sigmoid(g[0]);
    float fg = fast_sigmoid(g[1]);
    float gg = fast_tanh(g[2]);
    float og = fast_sigmoid(g[3]);
    float c  = fmaf(fg, cst, ig * gg);
    cst = c;
    return og * fast_tanh(c);
}

// Weights -> (hi,lo) frags. Frag k = ks*32 + kg*8 + e. Row N' = (T0+q)*16+m.
// L0M: [w_ih(8) | w_hh@k8..57 | bias@58]. MID: [w_ih@k0..49 | bias@50 |
// zeros | w_hh@k64..113 | zeros] (k-space matches granule-gather slots).
template<bool L0M, int NT, int KS>
__device__ __forceinline__ void load_wb(int T0, int lane,
    const float* __restrict__ w_ih, const float* __restrict__ w_hh,
    const float* __restrict__ b_ih, const float* __restrict__ b_hh,
    short8 (&Wh)[NT][KS], short8 (&Wl)[NT][KS])
{
    const int m = lane & 15, kg = lane >> 4;
    #pragma unroll
    for (int q = 0; q < NT; ++q) {
        int gp = (T0 + q) * 16 + m;
        int gr = (gp < 200) ? ((gp & 3) * 50 + (gp >> 2)) : -1;
        float bias = (gr >= 0) ? (b_ih[gr] + b_hh[gr]) : 0.0f;
        #pragma unroll
        for (int ks = 0; ks < KS; ++ks)
            #pragma unroll
            for (int e = 0; e < 8; ++e) {
                int k = ks * 32 + kg * 8 + e;
                float v = 0.0f;
                if (gr >= 0) {
                    if (L0M) {
                        if (k < 8) v = w_ih[gr * 8 + k];
                        else if (k < 58) v = w_hh[gr * 50 + (k - 8)];
                        else if (k == 58) v = bias;
                    } else {
                        if (k < 50) v = w_ih[gr * 50 + k];
                        else if (k == 50) v = bias;
                        else if (k >= 64 && k < 114) v = w_hh[gr * 50 + (k - 64)];
                    }
                }
                unsigned short hb = f2bf(v);
                Wh[q][ks][e] = (short)hb;
                Wl[q][ks][e] = (short)f2bf(v - bf2f(hb));
            }
    }
}

// One layer-step: batched frag reads -> 2-term MFMA -> in-register cell
// update -> single h write. GUARD: tile-12 roles (valid kg<2).
// DUAL: independent Wh/Wl acc chains (for NT=2 interleave depth).
template<int NT, int KS, bool ISMID, bool GUARD, bool LASTL, bool DUAL>
__device__ __forceinline__ void compute_step(
    int t, int T0, int lane,
    const short* xsb, const short* hsb, short* wb, float* hfp,
    const short8 (&Wh)[NT][KS], const short8 (&Wl)[NT][KS], float (&cst)[NT])
{
    const int b = lane & 15, kg = lane >> 4;

    short8 Ap[KS];
    #pragma unroll
    for (int ks = 0; ks < KS; ++ks) {
        if (!ISMID)
            Ap[ks] = *(const short8*)&xsb[(ks * 4 + kg) * GS + b * 8];
        else if (ks < 2)
            Ap[ks] = *(const short8*)&xsb[(1 + ks * 4 + kg) * GS + b * 8];
        else
            Ap[ks] = *(const short8*)&hsb[(1 + (ks - 2) * 4 + kg) * GS + b * 8];
    }

    f32x4 accA[NT], accB[NT];
    #pragma unroll
    for (int q = 0; q < NT; ++q) {
        accA[q] = (f32x4){0.0f, 0.0f, 0.0f, 0.0f};
        if (DUAL) accB[q] = (f32x4){0.0f, 0.0f, 0.0f, 0.0f};
    }
    #pragma unroll
    for (int ks = 0; ks < KS; ++ks)
        #pragma unroll
        for (int q = 0; q < NT; ++q)
            accA[q] = __builtin_amdgcn_mfma_f32_16x16x32_bf16(Wh[q][ks], Ap[ks], accA[q], 0, 0, 0);
    #pragma unroll
    for (int ks = 0; ks < KS; ++ks)
        #pragma unroll
        for (int q = 0; q < NT; ++q) {
            if (DUAL)
                accB[q] = __builtin_amdgcn_mfma_f32_16x16x32_bf16(Wl[q][ks], Ap[ks], accB[q], 0, 0, 0);
            else
                accA[q] = __builtin_amdgcn_mfma_f32_16x16x32_bf16(Wl[q][ks], Ap[ks], accA[q], 0, 0, 0);
        }

    #pragma unroll
    for (int q = 0; q < NT; ++q) {
        int u = (T0 + q) * 4 + kg;
        if (!GUARD || kg < 2) {
            f32x4 g4 = DUAL ? (accA[q] + accB[q]) : accA[q];
            float h = cell_upd(g4, cst[q]);
            unsigned short hb = f2bf(h);
            wb[(1 + (u >> 3)) * GS + b * 8 + (u & 7)] = (short)hb;
            if (LASTL && t == T_STEPS - 1) hfp[b * 56 + u] = h;
        }
    }
}

// L0 wave: NT=4 tiles (u<=47, no guard). XST: stage x(t+1) -> H0[(t+1)&1] g0.
template<int T0, bool XST>
__device__ void role_l0(int lane, int b0, const float* __restrict__ xf,
    const float* w_ih, const float* w_hh, const float* b_ih, const float* b_hh,
    short (*H0)[BUFSZ])
{
    short8 Wh[4][2], Wl[4][2];
    load_wb<true, 4, 2>(T0, lane, w_ih, w_hh, b_ih, b_hh, Wh, Wl);
    float cst[4] = {0.0f, 0.0f, 0.0f, 0.0f};
    const int bb = lane & 15, kg = lane >> 4;

    for (int it = 0; it < T_STEPS + 2; ++it) {
        const bool stg = XST && (kg == 0) && (it + 1 < T_STEPS);
        float xs[8];
        if (stg) {
            const float* xr = &xf[((size_t)(b0 + bb) * T_STEPS + (it + 1)) * 8];
            *(float4*)&xs[0] = *(const float4*)xr;
            *(float4*)&xs[4] = *(const float4*)(xr + 4);
        }
        if (it < T_STEPS)
            compute_step<4, 2, false, false, false, false>(it, T0, lane,
                H0[it & 1], nullptr, H0[(it + 1) & 1], nullptr, Wh, Wl, cst);
        if (stg) {
            short8 hi;
            #pragma unroll
            for (int e = 0; e < 8; ++e) hi[e] = (short)f2bf(xs[e]);
            *(short8*)&H0[(it + 1) & 1][bb * 8] = hi;
        }
        BAR();
    }
}

// Mid wave, NT=2. LASTL: L2 (skew 2, hf@t=255); else L1 (skew 1).
template<int T0, bool LASTL>
__device__ void role_mid(int lane,
    const float* w_ih, const float* w_hh, const float* b_ih, const float* b_hh,
    short (*H0)[BUFSZ], short (*H1)[BUFSZ], short (*H2)[BUFSZ], float* hfp)
{
    constexpr int SKEW = LASTL ? 2 : 1;
    short8 Wh[2][4], Wl[2][4];
    load_wb<false, 2, 4>(T0, lane, w_ih, w_hh, b_ih, b_hh, Wh, Wl);
    float cst[2] = {0.0f, 0.0f};
    int m0 = 0, m1 = 2, m2 = 1;      // it%3, (it-1)%3, (it-2)%3

    for (int it = 0; it < T_STEPS + 2; ++it) {
        int t = it - SKEW;
        if (0 <= t && t < T_STEPS) {
            if (!LASTL)   // L1: x-side = h0(t) in H0[it&1]; h-side = h1(t-1); write h1(t)
                compute_step<2, 4, true, false, false, true>(t, T0, lane,
                    H0[it & 1], H1[m2], H1[m1], nullptr, Wh, Wl, cst);
            else          // L2: x-side = h1(t) in H1[t%3]; h-side = h2(t-1); write h2(t)
                compute_step<2, 4, true, false, true, true>(t, T0, lane,
                    H1[m2], H2[(it + 1) & 1], H2[it & 1], hfp, Wh, Wl, cst);
        }
        BAR();
        int tmp = m2; m2 = m1; m1 = m0; m0 = tmp;
    }
}

// Orphan: tile 12 of L0 (skew0), L1 (skew1), L2 (skew2); units 48,49 (kg<2).
__device__ void role_orphan(int lane,
    const float* w_ih0, const float* w_hh0, const float* b_ih0, const float* b_hh0,
    const float* w_ih1, const float* w_hh1, const float* b_ih1, const float* b_hh1,
    const float* w_ih2, const float* w_hh2, const float* b_ih2, const float* b_hh2,
    short (*H0)[BUFSZ], short (*H1)[BUFSZ], short (*H2)[BUFSZ], float* hfp)
{
    short8 W0h[1][2], W0l[1][2], W1h[1][4], W1l[1][4], W2h[1][4], W2l[1][4];
    load_wb<true, 1, 2>(12, lane, w_ih0, w_hh0, b_ih0, b_hh0, W0h, W0l);
    load_wb<false, 1, 4>(12, lane, w_ih1, w_hh1, b_ih1, b_hh1, W1h, W1l);
    load_wb<false, 1, 4>(12, lane, w_ih2, w_hh2, b_ih2, b_hh2, W2h, W2l);
    float c0[1] = {0.0f}, c1[1] = {0.0f}, c2[1] = {0.0f};
    int m0 = 0, m1 = 2, m2 = 1;

    for (int it = 0; it < T_STEPS + 2; ++it) {
        if (it < T_STEPS)
            compute_step<1, 2, false, true, false, false>(it, 12, lane,
                H0[it & 1], nullptr, H0[(it + 1) & 1], nullptr, W0h, W0l, c0);
        int t1 = it - 1;
        if ((unsigned)t1 < T_STEPS)
            compute_step<1, 4, true, true, false, false>(t1, 12, lane,
                H0[it & 1], H1[m2], H1[m1], nullptr, W1h, W1l, c1);
        int t2 = it - 2;
        if ((unsigned)t2 < T_STEPS)
            compute_step<1, 4, true, true, true, false>(t2, 12, lane,
                H1[m2], H2[(it + 1) & 1], H2[it & 1], hfp, W2h, W2l, c2);
        BAR();
        int tmp = m2; m2 = m1; m1 = m0; m0 = tmp;
    }
}

__global__ __launch_bounds__(NTHR, 4) void lstm_fused(
    const float* __restrict__ xf,
    const float* w_ih0, const float* w_hh0, const float* b_ih0, const float* b_hh0,
    const float* w_ih1, const float* w_hh1, const float* b_ih1, const float* b_hh1,
    const float* w_ih2, const float* w_hh2, const float* b_ih2, const float* b_hh2,
    const float* __restrict__ w_fc, const float* __restrict__ b_fc,
    float* __restrict__ out)
{
    __shared__ __align__(16) short H0[2][BUFSZ];
    __shared__ __align__(16) short H1[3][BUFSZ];
    __shared__ __align__(16) short H2[2][BUFSZ];
    __shared__ __align__(16) float hf[16 * 56];

    const int tid  = threadIdx.x;
    const int lane = tid & 63;
    const int wid  = tid >> 6;
    const int b0   = blockIdx.x * 16;

    for (int i = tid; i < 2 * BUFSZ; i += NTHR) { H0[0][i] = 0; }
    for (int i = tid; i < 3 * BUFSZ; i += NTHR) { ((short*)H1)[i] = 0; }
    for (int i = tid; i < 2 * BUFSZ; i += NTHR) { ((short*)H2)[i] = 0; }
    __syncthreads();

    // bias act columns (unit index 50 -> granule 7 pos 2) = 1.0 in all bufs
    if (tid < 112) {
        int bufi = tid >> 4, b = tid & 15;
        short* bp = (bufi < 2) ? H0[bufi] : ((bufi < 5) ? H1[bufi - 2] : H2[bufi - 5]);
        bp[7 * GS + b * 8 + 2] = (short)0x3F80;
    }
    // x(0) -> H0[0] granule 0
    if (tid < 16) {
        int b = tid;
        #pragma unroll
        for (int j = 0; j < 8; ++j) {
            float v = xf[((size_t)(b0 + b) * T_STEPS + 0) * 8 + j];
            H0[0][b * 8 + j] = (short)f2bf(v);
        }
    }
    __syncthreads();

    // 16 waves; roles interleaved so wid&3 (SIMD) gets a mix.
    if      (wid == 0)  role_l0<0, false>(lane, b0, xf, w_ih0, w_hh0, b_ih0, b_hh0, H0);
    else if (wid == 1)  role_l0<4, false>(lane, b0, xf, w_ih0, w_hh0, b_ih0, b_hh0, H0);
    else if (wid == 2)  role_l0<8, true >(lane, b0, xf, w_ih0, w_hh0, b_ih0, b_hh0, H0);
    else if (wid == 3)  role_orphan(lane,
                            w_ih0, w_hh0, b_ih0, b_hh0,
                            w_ih1, w_hh1, b_ih1, b_hh1,
                            w_ih2, w_hh2, b_ih2, b_hh2, H0, H1, H2, hf);
    else if (wid == 4)  role_mid<0,  false>(lane, w_ih1, w_hh1, b_ih1, b_hh1, H0, H1, H2, nullptr);
    else if (wid == 5)  role_mid<2,  false>(lane, w_ih1, w_hh1, b_ih1, b_hh1, H0, H1, H2, nullptr);
    else if (wid == 6)  role_mid<4,  false>(lane, w_ih1, w_hh1, b_ih1, b_hh1, H0, H1, H2, nullptr);
    else if (wid == 7)  role_mid<6,  false>(lane, w_ih1, w_hh1, b_ih1, b_hh1, H0, H1, H2, nullptr);
    else if (wid == 8)  role_mid<8,  false>(lane, w_ih1, w_hh1, b_ih1, b_hh1, H0, H1, H2, nullptr);
    else if (wid == 9)  role_mid<10, false>(lane, w_ih1, w_hh1, b_ih1, b_hh1, H0, H1, H2, nullptr);
    else if (wid == 10) role_mid<0,  true >(lane, w_ih2, w_hh2, b_ih2, b_hh2, H0, H1, H2, hf);
    else if (wid == 11) role_mid<2,  true >(lane, w_ih2, w_hh2, b_ih2, b_hh2, H0, H1, H2, hf);
    else if (wid == 12) role_mid<4,  true >(lane, w_ih2, w_hh2, b_ih2, b_hh2, H0, H1, H2, hf);
    else if (wid == 13) role_mid<6,  true >(lane, w_ih2, w_hh2, b_ih2, b_hh2, H0, H1, H2, hf);
    else if (wid == 14) role_mid<8,  true >(lane, w_ih2, w_hh2, b_ih2, b_hh2, H0, H1, H2, hf);
    else                role_mid<10, true >(lane, w_ih2, w_hh2, b_ih2, b_hh2, H0, H1, H2, hf);

    __syncthreads();

    if (tid < 96) {
        int b = tid / 6, o = tid - b * 6;
        float a = b_fc[o];
        #pragma unroll
        for (int n = 0; n < 50; ++n)
            a = fmaf(w_fc[o * 50 + n], hf[b * 56 + n], a);
        out[(size_t)(b0 + b) * 6 + o] = a;
    }
}

extern "C" void kernel_launch(void* const* d_in, const int* in_sizes, int n_in,
                              void* d_out, int out_size, void* d_ws, size_t ws_size,
                              hipStream_t stream) {
    (void)in_sizes; (void)n_in; (void)d_ws; (void)ws_size; (void)out_size;

    const float* x     = (const float*)d_in[0];
    const float* w_ih0 = (const float*)d_in[1];
    const float* w_hh0 = (const float*)d_in[2];
    const float* b_ih0 = (const float*)d_in[3];
    const float* b_hh0 = (const float*)d_in[4];
    const float* w_ih1 = (const float*)d_in[5];
    const float* w_hh1 = (const float*)d_in[6];
    const float* b_ih1 = (const float*)d_in[7];
    const float* b_hh1 = (const float*)d_in[8];
    const float* w_ih2 = (const float*)d_in[9];
    const float* w_hh2 = (const float*)d_in[10];
    const float* b_ih2 = (const float*)d_in[11];
    const float* b_hh2 = (const float*)d_in[12];
    const float* w_fc  = (const float*)d_in[13];
    const float* b_fc  = (const float*)d_in[14];
    float* out = (float*)d_out;

    lstm_fused<<<dim3(BTOT / 16), dim3(NTHR), 0, stream>>>(
        x, w_ih0, w_hh0, b_ih0, b_hh0, w_ih1, w_hh1, b_ih1, b_hh1,
        w_ih2, w_hh2, b_ih2, b_hh2, w_fc, b_fc, out);
}